// Round 3
// baseline (94.948 us; speedup 1.0000x reference)
//
#include <hip/hip_runtime.h>
#include <hip/hip_bf16.h>

#define NS   16384
#define FKD  2048
#define CD   100
#define CP   112
#define MT   64
#define EPSF 1e-8f
#define SFK  (FKD * CP)          // 229376 elements of the reduced S matrix
#define NGRP (NS / 8)            // 2048 k-groups of 8

typedef float f32x4 __attribute__((ext_vector_type(4)));
typedef float f32x8 __attribute__((ext_vector_type(8)));
typedef short bf16x8 __attribute__((ext_vector_type(8)));

__device__ inline unsigned short f2bf(float f) {
    unsigned int u = __float_as_uint(f);
    u += 0x7FFFu + ((u >> 16) & 1u);   // RNE; inputs are finite in [0,1]
    return (unsigned short)(u >> 16);
}

// ---------------- prep: teacher -> bf16 fragment layout ----------------
// Bp[g][c][j] = bf16(tp[(8g+j)*CD + c]) ; col CD == 1.0 (bin-mass column), >CD == 0
__global__ __launch_bounds__(256) void ebl_prep(
    const float* __restrict__ tp, unsigned short* __restrict__ Bp)
{
    const int idx = blockIdx.x * 256 + threadIdx.x;     // (g, c)
    if (idx >= NGRP * CP) return;
    const int g = idx / CP, c = idx - g * CP;
    unsigned short v[8];
    if (c < CD) {
        const float* p = tp + (size_t)g * 8 * CD + c;
        #pragma unroll
        for (int j = 0; j < 8; ++j) v[j] = f2bf(p[(size_t)j * CD]);
    } else {
        const unsigned short fill = (c == CD) ? 0x3F80 : 0;   // bf16(1.0) / 0
        #pragma unroll
        for (int j = 0; j < 8; ++j) v[j] = fill;
    }
    *reinterpret_cast<uint4*>(Bp + (size_t)idx * 8) = *reinterpret_cast<const uint4*>(v);
}

// ---------------- GEMM: barrier-free, double-buffered register pipeline ----------------
// S_partial[kc][m][c] (bf16) = sum over k-chunk of bf16(mem[n][m]) * Bp[n][c]
__global__ __launch_bounds__(256, 4) void ebl_gemm(
    const float* __restrict__ mem, const unsigned short* __restrict__ Bp,
    unsigned short* __restrict__ spart, int steps)
{
    const int t  = threadIdx.x;
    const int w  = t >> 6;                 // wave -> m-subtile
    const int l  = t & 63;
    const int lg = l >> 4, lr = l & 15;
    const int m  = blockIdx.x * MT + w * 16 + lr;
    const int kc = blockIdx.y;
    const int g0 = kc * steps * 4 + lg;    // this lane's first k-group

    const float*          ap = mem + (size_t)g0 * 8 * FKD + m;
    const unsigned short* bp = Bp + ((size_t)g0 * CP + lr) * 8;
    const size_t aStep = (size_t)32 * FKD;   // one k-phase = 32 n-rows
    const size_t bStep = (size_t)4 * CP * 8;

    f32x4 acc[7];
    #pragma unroll
    for (int i = 0; i < 7; ++i) acc[i] = (f32x4){0.f, 0.f, 0.f, 0.f};

    float a0[8], a1[8]; bf16x8 b0[7], b1[7];

#define LOADA(dst, base) { \
    const float* _p = (base); \
    _Pragma("unroll") \
    for (int j = 0; j < 8; ++j) dst[j] = __builtin_nontemporal_load(_p + (size_t)j * FKD); }
#define LOADB(dst, base) { \
    const unsigned short* _q = (base); \
    _Pragma("unroll") \
    for (int nt = 0; nt < 7; ++nt) dst[nt] = *reinterpret_cast<const bf16x8*>(_q + nt * 128); }
#define COMPUTE(aB, bB) { \
    bf16x8 af; \
    _Pragma("unroll") \
    for (int j = 0; j < 8; ++j) af[j] = (short)f2bf(aB[j]); \
    _Pragma("unroll") \
    for (int nt = 0; nt < 7; ++nt) \
        acc[nt] = __builtin_amdgcn_mfma_f32_16x16x32_bf16(af, bB[nt], acc[nt], 0, 0, 0); }

    LOADA(a0, ap);             LOADB(b0, bp);
    LOADA(a1, ap + aStep);     LOADB(b1, bp + bStep);

    // steps is even (16/32/64) by construction
    for (int s = 0; s < steps - 2; s += 2) {
        COMPUTE(a0, b0);
        LOADA(a0, ap + 2 * aStep);  LOADB(b0, bp + 2 * bStep);
        COMPUTE(a1, b1);
        LOADA(a1, ap + 3 * aStep);  LOADB(b1, bp + 3 * bStep);
        ap += 2 * aStep; bp += 2 * bStep;
    }
    COMPUTE(a0, b0);
    COMPUTE(a1, b1);

#undef LOADA
#undef LOADB
#undef COMPUTE

    // C/D layout: col = lane&15, row = (lane>>4)*4 + reg   [verified rounds 1-2]
    unsigned short* sp = spart + (size_t)kc * SFK;
    #pragma unroll
    for (int nt = 0; nt < 7; ++nt) {
        const int c = nt * 16 + lr;
        #pragma unroll
        for (int r = 0; r < 4; ++r) {
            const int mm = blockIdx.x * MT + w * 16 + lg * 4 + r;
            sp[(size_t)mm * CP + c] = f2bf(acc[nt][r]);
        }
    }
}

// ---------------- reduce split-K partials (bf16 -> fp32, vectorized) ----------------
__global__ __launch_bounds__(256) void ebl_reduce(
    const unsigned short* __restrict__ spart, float* __restrict__ S, int NK)
{
    const int v = blockIdx.x * 256 + threadIdx.x;    // 8-element vector id
    if (v >= SFK / 8) return;
    float s[8];
    #pragma unroll
    for (int j = 0; j < 8; ++j) s[j] = 0.f;
    for (int p = 0; p < NK; ++p) {
        uint4 raw = *reinterpret_cast<const uint4*>(spart + (size_t)p * SFK + (size_t)v * 8);
        const unsigned short* u = reinterpret_cast<const unsigned short*>(&raw);
        #pragma unroll
        for (int j = 0; j < 8; ++j) s[j] += __uint_as_float((unsigned)u[j] << 16);
    }
    f32x4* out = reinterpret_cast<f32x4*>(S + (size_t)v * 8);
    out[0] = (f32x4){s[0], s[1], s[2], s[3]};
    out[1] = (f32x4){s[4], s[5], s[6], s[7]};
}

// ---------------- entropies per f, partial losses ----------------
__global__ __launch_bounds__(256) void ebl_entropy(
    const float* __restrict__ S, float* __restrict__ fpart)
{
    __shared__ float Ss[32 * CP];
    __shared__ float massL[32];
    __shared__ float red[4];
    const int t = threadIdx.x;
    const int f = blockIdx.x;

    for (int idx = t; idx < 32 * CP; idx += 256)
        Ss[idx] = S[(size_t)f * 32 * CP + idx];
    __syncthreads();
    if (t < 32) massL[t] = Ss[t * CP + CD] + EPSF;   // ones-column = bin mass (+EPS)
    __syncthreads();

    float a_int = 0.f, a_mix = 0.f;
    for (int idx = t; idx < 32 * CD; idx += 256) {
        const int k = idx / CD, c = idx - k * CD;
        const float cent = Ss[k * CP + c] / massL[k];
        a_int -= cent * logf(cent + EPSF) * massL[k];
    }
    for (int idx = t; idx < 31 * CD; idx += 256) {
        const int k = idx / CD, c = idx - k * CD;
        const float mix = 0.5f * (Ss[k * CP + c] / massL[k] + Ss[(k + 1) * CP + c] / massL[k + 1]);
        a_mix += mix * logf(mix + EPSF);
    }

    float part = a_int * (1.0f / (float)NS) + 0.5f * a_mix;
    #pragma unroll
    for (int off = 32; off > 0; off >>= 1) part += __shfl_down(part, off);
    if ((t & 63) == 0) red[t >> 6] = part;
    __syncthreads();
    if (t == 0) fpart[f] = (red[0] + red[1]) + (red[2] + red[3]);
}

__global__ void ebl_finalize(const float* __restrict__ fpart, float* __restrict__ out) {
    float v = fpart[threadIdx.x];
    #pragma unroll
    for (int off = 32; off > 0; off >>= 1) v += __shfl_down(v, off);
    if (threadIdx.x == 0) out[0] = v;
}

extern "C" void kernel_launch(void* const* d_in, const int* in_sizes, int n_in,
                              void* d_out, int out_size, void* d_ws, size_t ws_size,
                              hipStream_t stream)
{
    const float* mem = (const float*)d_in[0];
    const float* tp  = (const float*)d_in[1];
    float* out = (float*)d_out;

    const size_t bpBytes = (size_t)NGRP * CP * 8 * 2;    // 3,670,016 B (16-aligned)

    int NK = 32;
    while (NK > 1 &&
           bpBytes + (size_t)NK * SFK * 2 + ((size_t)SFK + 64) * 4 > ws_size) NK >>= 1;
    const int steps = NS / (NK * 32);   // 16 / 32 / 64 ... always even

    unsigned short* Bp    = (unsigned short*)d_ws;
    unsigned short* spart = (unsigned short*)((char*)d_ws + bpBytes);
    float*          S     = (float*)((char*)spart + (size_t)NK * SFK * 2);
    float*          fpart = S + SFK;

    ebl_prep<<<(NGRP * CP + 255) / 256, 256, 0, stream>>>(tp, Bp);
    dim3 grid(FKD / MT, NK);
    ebl_gemm<<<grid, 256, 0, stream>>>(mem, Bp, spart, steps);
    ebl_reduce<<<(SFK / 8 + 255) / 256, 256, 0, stream>>>(spart, S, NK);
    ebl_entropy<<<64, 256, 0, stream>>>(S, fpart);
    ebl_finalize<<<1, 64, 0, stream>>>(fpart, out);
}

// Round 4
// 73.970 us; speedup vs baseline: 1.2836x; 1.2836x over previous
//
#include <hip/hip_runtime.h>
#include <hip/hip_bf16.h>

#define NS   16384
#define FKD  2048
#define CD   100
#define CP   112
#define MT   64
#define EPSF 1e-8f
#define SFK  (FKD * CP)          // 229376 elements of one S partial
#define NGRP (NS / 8)            // 2048 k-groups of 8

typedef float f32x4 __attribute__((ext_vector_type(4)));
typedef short bf16x8 __attribute__((ext_vector_type(8)));

__device__ inline unsigned short f2bf(float f) {
    unsigned int u = __float_as_uint(f);
    u += 0x7FFFu + ((u >> 16) & 1u);   // RNE; inputs are finite in [0,1]
    return (unsigned short)(u >> 16);
}

// ---------------- prep: teacher -> bf16 fragment layout ----------------
// Bp[g][c][j] = bf16(tp[(8g+j)*CD + c]) ; col CD == 1.0 (bin-mass column), >CD == 0
__global__ __launch_bounds__(256) void ebl_prep(
    const float* __restrict__ tp, unsigned short* __restrict__ Bp)
{
    const int idx = blockIdx.x * 256 + threadIdx.x;     // (g, c)
    if (idx >= NGRP * CP) return;
    const int g = idx / CP, c = idx - g * CP;
    unsigned short v[8];
    if (c < CD) {
        const float* p = tp + (size_t)g * 8 * CD + c;
        #pragma unroll
        for (int j = 0; j < 8; ++j) v[j] = f2bf(p[(size_t)j * CD]);
    } else {
        const unsigned short fill = (c == CD) ? 0x3F80 : 0;   // bf16(1.0) / 0
        #pragma unroll
        for (int j = 0; j < 8; ++j) v[j] = fill;
    }
    *reinterpret_cast<uint4*>(Bp + (size_t)idx * 8) = *reinterpret_cast<const uint4*>(v);
}

// ---------------- GEMM: barrier-free, A distance-2 / B distance-1 pipeline ----------------
// S_partial[kc][m][c] (bf16) = sum over k-chunk of bf16(mem[n][m]) * Bp[n][c]
__global__ __launch_bounds__(256, 4) void ebl_gemm(
    const float* __restrict__ mem, const unsigned short* __restrict__ Bp,
    unsigned short* __restrict__ spart, int steps)
{
    const int t  = threadIdx.x;
    const int w  = t >> 6;                 // wave -> m-subtile
    const int l  = t & 63;
    const int lg = l >> 4, lr = l & 15;
    const int m  = blockIdx.x * MT + w * 16 + lr;
    const int kc = blockIdx.y;
    const int g0 = kc * steps * 4 + lg;    // this lane's first k-group

    const float*          ap = mem + (size_t)g0 * 8 * FKD + m;
    const unsigned short* bp = Bp + ((size_t)g0 * CP + lr) * 8;
    const size_t aStep = (size_t)32 * FKD;   // one k-phase = 32 n-rows
    const size_t bStep = (size_t)4 * CP * 8;

    f32x4 acc[7];
    #pragma unroll
    for (int i = 0; i < 7; ++i) acc[i] = (f32x4){0.f, 0.f, 0.f, 0.f};

    float a0[8], a1[8]; bf16x8 b0[7], b1[7];

#define LOADA(dst, base) { \
    const float* _p = (base); \
    _Pragma("unroll") \
    for (int j = 0; j < 8; ++j) dst[j] = _p[(size_t)j * FKD]; }
#define LOADB(dst, base) { \
    const unsigned short* _q = (base); \
    _Pragma("unroll") \
    for (int nt = 0; nt < 7; ++nt) dst[nt] = *reinterpret_cast<const bf16x8*>(_q + nt * 128); }
#define COMPUTE(aB, bB) { \
    bf16x8 af; \
    _Pragma("unroll") \
    for (int j = 0; j < 8; ++j) af[j] = (short)f2bf(aB[j]); \
    _Pragma("unroll") \
    for (int nt = 0; nt < 7; ++nt) \
        acc[nt] = __builtin_amdgcn_mfma_f32_16x16x32_bf16(af, bB[nt], acc[nt], 0, 0, 0); }

    LOADA(a0, ap);             LOADB(b0, bp);
    LOADA(a1, ap + aStep);     LOADB(b1, bp + bStep);

    // steps is even (16/32/64) by construction
    for (int s = 0; s < steps - 2; s += 2) {
        COMPUTE(a0, b0);
        LOADA(a0, ap + 2 * aStep);  LOADB(b0, bp + 2 * bStep);
        COMPUTE(a1, b1);
        LOADA(a1, ap + 3 * aStep);  LOADB(b1, bp + 3 * bStep);
        ap += 2 * aStep; bp += 2 * bStep;
    }
    COMPUTE(a0, b0);
    COMPUTE(a1, b1);

#undef LOADA
#undef LOADB
#undef COMPUTE

    // C/D layout: col = lane&15, row = (lane>>4)*4 + reg   [verified rounds 1-3]
    unsigned short* sp = spart + (size_t)kc * SFK;
    #pragma unroll
    for (int nt = 0; nt < 7; ++nt) {
        const int c = nt * 16 + lr;
        #pragma unroll
        for (int r = 0; r < 4; ++r) {
            const int mm = blockIdx.x * MT + w * 16 + lg * 4 + r;
            sp[(size_t)mm * CP + c] = f2bf(acc[nt][r]);
        }
    }
}

// ---------------- fused: sum split-K partials + entropies per f ----------------
__global__ __launch_bounds__(256) void ebl_entropy(
    const unsigned short* __restrict__ spart, int NK, float* __restrict__ fpart)
{
    __shared__ float Ss[32 * CP];
    __shared__ float massL[32];
    __shared__ float red[4];
    const int t = threadIdx.x;
    const int f = blockIdx.x;
    const size_t base = (size_t)f * 32 * CP;   // 3584 contiguous elements per partial

    // vectorized bf16 sum across NK partials: 3584/8 = 448 uint4 vectors
    for (int v = t; v < 32 * CP / 8; v += 256) {
        float s[8];
        #pragma unroll
        for (int j = 0; j < 8; ++j) s[j] = 0.f;
        for (int p = 0; p < NK; ++p) {
            uint4 raw = *reinterpret_cast<const uint4*>(spart + (size_t)p * SFK + base + (size_t)v * 8);
            const unsigned short* u = reinterpret_cast<const unsigned short*>(&raw);
            #pragma unroll
            for (int j = 0; j < 8; ++j) s[j] += __uint_as_float((unsigned)u[j] << 16);
        }
        #pragma unroll
        for (int j = 0; j < 8; ++j) Ss[v * 8 + j] = s[j];
    }
    __syncthreads();
    if (t < 32) massL[t] = Ss[t * CP + CD] + EPSF;   // ones-column = bin mass (+EPS)
    __syncthreads();

    float a_int = 0.f, a_mix = 0.f;
    for (int idx = t; idx < 32 * CD; idx += 256) {
        const int k = idx / CD, c = idx - k * CD;
        const float cent = Ss[k * CP + c] / massL[k];
        a_int -= cent * logf(cent + EPSF) * massL[k];
    }
    for (int idx = t; idx < 31 * CD; idx += 256) {
        const int k = idx / CD, c = idx - k * CD;
        const float mix = 0.5f * (Ss[k * CP + c] / massL[k] + Ss[(k + 1) * CP + c] / massL[k + 1]);
        a_mix += mix * logf(mix + EPSF);
    }

    float part = a_int * (1.0f / (float)NS) + 0.5f * a_mix;
    #pragma unroll
    for (int off = 32; off > 0; off >>= 1) part += __shfl_down(part, off);
    if ((t & 63) == 0) red[t >> 6] = part;
    __syncthreads();
    if (t == 0) fpart[f] = (red[0] + red[1]) + (red[2] + red[3]);
}

__global__ void ebl_finalize(const float* __restrict__ fpart, float* __restrict__ out) {
    float v = fpart[threadIdx.x];
    #pragma unroll
    for (int off = 32; off > 0; off >>= 1) v += __shfl_down(v, off);
    if (threadIdx.x == 0) out[0] = v;
}

extern "C" void kernel_launch(void* const* d_in, const int* in_sizes, int n_in,
                              void* d_out, int out_size, void* d_ws, size_t ws_size,
                              hipStream_t stream)
{
    const float* mem = (const float*)d_in[0];
    const float* tp  = (const float*)d_in[1];
    float* out = (float*)d_out;

    const size_t bpBytes = (size_t)NGRP * CP * 8 * 2;    // 3,670,016 B (16-aligned)

    int NK = 32;
    while (NK > 1 && bpBytes + (size_t)NK * SFK * 2 + 64 * 4 > ws_size) NK >>= 1;
    const int steps = NS / (NK * 32);   // 16 for NK=32 ... always even

    unsigned short* Bp    = (unsigned short*)d_ws;
    unsigned short* spart = (unsigned short*)((char*)d_ws + bpBytes);
    float*          fpart = (float*)((char*)spart + (size_t)NK * SFK * 2);

    ebl_prep<<<(NGRP * CP + 255) / 256, 256, 0, stream>>>(tp, Bp);
    dim3 grid(FKD / MT, NK);
    ebl_gemm<<<grid, 256, 0, stream>>>(mem, Bp, spart, steps);
    ebl_entropy<<<64, 256, 0, stream>>>(spart, NK, fpart);
    ebl_finalize<<<1, 64, 0, stream>>>(fpart, out);
}